// Round 5
// baseline (43521.555 us; speedup 1.0000x reference)
//
#include <hip/hip_runtime.h>
#include <math.h>

#define TPB 256
#define NBLK 512

typedef unsigned short u16;
typedef float f32x4 __attribute__((ext_vector_type(4)));
typedef short s16x8 __attribute__((ext_vector_type(8)));
typedef unsigned int u32x4 __attribute__((ext_vector_type(4)));

// ---------------- helpers ----------------
__device__ __forceinline__ u16 f2bf(float f) {
  unsigned u = __float_as_uint(f);
  unsigned r = (u + 0x7FFFu + ((u >> 16) & 1u)) >> 16;   // RNE
  return (u16)r;
}
__device__ __forceinline__ float bf2f(u16 b) { return __uint_as_float(((unsigned)b) << 16); }
__device__ __forceinline__ float sigm(float x) { return 1.f / (1.f + expf(-x)); }

__device__ __forceinline__ f32x4 mfma_bf16(s16x8 a, s16x8 b, f32x4 c) {
  return __builtin_amdgcn_mfma_f32_16x16x32_bf16(a, b, c, 0, 0, 0);
}

// ---- asm memory ops. sc1 = device scope (meet at LLC); plain = cached (L1/L2).
// All K-loop VMEM is asm ("memory"-clobbered) so manual vmcnt discipline is exact
// and the compiler cannot interleave its own loads into the accounting window.
__device__ __forceinline__ u32x4 ld_sc1_x4(const void* p) {
  u32x4 d;
  asm volatile("global_load_dwordx4 %0, %1, off sc1"
               : "=v"(d) : "v"((unsigned long long)p) : "memory");
  return d;
}
__device__ __forceinline__ s16x8 ld_b16x8(const void* p) {  // cached (weights)
  s16x8 d;
  asm volatile("global_load_dwordx4 %0, %1, off"
               : "=v"(d) : "v"((unsigned long long)p) : "memory");
  return d;
}
__device__ __forceinline__ void st_sc1_x4(void* p, u32x4 v) {
  asm volatile("global_store_dwordx4 %0, %1, off sc1"
               :: "v"((unsigned long long)p), "v"(v) : "memory");
}
__device__ __forceinline__ void wait_vm0() { asm volatile("s_waitcnt vmcnt(0)" ::: "memory"); }
#define WAITVM(n) asm volatile("s_waitcnt vmcnt(" #n ")" ::: "memory")
// pin: redefine a value after a manual wait so no consumer can float above it.
__device__ __forceinline__ void pin(u32x4& v) { asm volatile("" : "+v"(v)); }
__device__ __forceinline__ void pin(s16x8& v) { asm volatile("" : "+v"(v)); }

// ---------------- params ----------------
struct KParams {
  const float* x;          // [1024][336][16]
  float* out;              // [1024][168]
  unsigned long long* cx;  // per-group barrier counters (stride 32 ULL = 256B)
  unsigned long long* cg;  // global barrier counter
  u16* h0h[2]; u16* h1h[2];  // h frag-layout [16][1024][32] bf16 HI only, ping-pong (sc1)
  const u16 *we0h, *we0l;    // [17][2048][32] (chunk 16 = x weights)
  const u16 *we1h, *we1l;    // [32][2048][32]
  const u16 *wd0h, *wd0l;    // [16][2048][32]
  const u16 *wd1h, *wd1l;    // [32][2048][32]
  const u16 *wfh;            // [16][256][32] (hi only used)
  const float *be0, *be1, *bd0, *bd1, *wyp;  // permuted biases [2048], dec0 y-column [2048]
  const float *fcb1, *fcw2, *fcb2;           // raw fp32 from inputs
};

// ---------------- init kernels ----------------
__global__ void zero_ws(uint4* p, long n) {
  uint4 z = {0u, 0u, 0u, 0u};
  for (long i = (long)blockIdx.x * blockDim.x + threadIdx.x; i < n; i += (long)gridDim.x * blockDim.x)
    p[i] = z;
}

// Build fragment-major, gate-interleaved, hi/lo-split weights.
// dst[c][n'][kk], n' = h*4+g  (orig row n = g*512+h), k = c*32+kk.
__global__ void prep_w(const float* __restrict__ Wih, const float* __restrict__ Whh,
                       const float* __restrict__ bias,
                       u16* __restrict__ dhi, u16* __restrict__ dlo,
                       float* __restrict__ bias_p, float* __restrict__ wy_p,
                       int mode, int nchunks) {
  long total = (long)nchunks * 2048 * 32;
  for (long i = (long)blockIdx.x * blockDim.x + threadIdx.x; i < total; i += (long)gridDim.x * blockDim.x) {
    int kk = (int)(i & 31);
    long r1 = i >> 5;
    int n = (int)(r1 & 2047);
    int c = (int)(r1 >> 11);
    int h = n >> 2, g = n & 3;
    int no = g * 512 + h;
    float wv;
    if (mode == 0)      wv = (c < 16) ? Whh[no * 512 + c * 32 + kk] : (kk < 16 ? Wih[no * 16 + kk] : 0.f);
    else if (mode == 1) wv = (c < 16) ? Wih[no * 512 + c * 32 + kk] : Whh[no * 512 + (c - 16) * 32 + kk];
    else                wv = Whh[no * 512 + c * 32 + kk];
    u16 hb = f2bf(wv);
    dhi[i] = hb;
    dlo[i] = f2bf(wv - bf2f(hb));
    if (i < 2048) {
      int nn = (int)i, hh = nn >> 2, gg = nn & 3, noo = gg * 512 + hh;
      bias_p[nn] = bias[noo];
      if (mode == 2) wy_p[nn] = Wih[noo];  // dec_Wih0 is [2048][1]
    }
  }
}

__global__ void prep_fc(const float* __restrict__ W1, u16* __restrict__ dhi) {
  int total = 16 * 256 * 32;
  for (int i = blockIdx.x * blockDim.x + threadIdx.x; i < total; i += gridDim.x * blockDim.x) {
    int kk = i & 31, n = (i >> 5) & 255, c = i >> 13;
    dhi[i] = f2bf(W1[n * 512 + c * 32 + kk]);
  }
}

// ---------------- fence-free grid barrier: one arrival per block ----------------
// All bulk data moves via sc1 ops drained by wait_vm0 before arrival -> no cache
// maintenance. 64 blocks/group arrive on cx[grp]; group-last bumps cg.
__device__ __forceinline__ void gbar(const KParams& P, int grp, unsigned long long bi) {
  wait_vm0();       // per-wave: this wave's sc1 stores are at the LLC
  __syncthreads();  // all 4 waves drained
  if (threadIdx.x == 0) {
    unsigned long long old =
        __hip_atomic_fetch_add(&P.cx[grp * 32], 1ULL, __ATOMIC_RELAXED, __HIP_MEMORY_SCOPE_AGENT);
    if (old == bi * 64ULL - 1ULL)
      __hip_atomic_fetch_add(P.cg, 1ULL, __ATOMIC_RELAXED, __HIP_MEMORY_SCOPE_AGENT);
    unsigned long long t0 = __builtin_amdgcn_s_memrealtime();
    while (__hip_atomic_load(P.cg, __ATOMIC_RELAXED, __HIP_MEMORY_SCOPE_AGENT) < bi * 8ULL) {
      __builtin_amdgcn_s_sleep(4);
      if (__builtin_amdgcn_s_memrealtime() - t0 > 300000000ULL) {  // ~3 s
        P.out[0] = 1e9f;  // sentinel: barrier timeout
        break;
      }
    }
  }
  __syncthreads();
}

// ---------------- fused gates GEMM + LSTM cell ----------------
// 32m x 128n tile (512 blocks = 32 m_tiles x 16 n_tiles, 2 blocks/CU).
// A = activations bf16 HI only (sc1 from LLC), staged via double-buffered LDS.
// B = weights bf16 hi+lo, per-wave regs from L2. 2 MFMAs per (ch,mr,mi):
// Ah*Bh + Ah*Bl. c-state in registers. Pipeline: A 4 stages ahead (1 load/thr),
// B 2 ahead (8/thr); steady wait vmcnt(10) - never drains mid-loop.
template <int NCT, bool TWOA, bool HASX, bool HASY>
__device__ __forceinline__ void lstm_phase(
    const KParams& P, int m_tile, int n_tile,
    const u16* A1h, const u16* A2h,
    const u16* WBh, const u16* WBl,
    const float* __restrict__ bias_p, const float* __restrict__ wyp, int t,
    float (&creg)[4], u16* Hh, char* smem, const float* yb) {
  constexpr int NST = NCT / 2;
  const int tid = threadIdx.x;
  const int w = tid >> 6, lane = tid & 63, r = lane & 15, q = lane >> 4;
  const int m0 = m_tile * 32, n0 = n_tile * 128;
  u16* sA = (u16*)smem;  // 2 bufs x [2ch][32r][40] u16 = 10240 B
  const int ch_ld = tid >> 7, rr = (tid >> 2) & 31, seg = tid & 3;

  f32x4 acc[2][2];
#pragma unroll
  for (int mr = 0; mr < 2; ++mr)
#pragma unroll
    for (int mi = 0; mi < 2; ++mi) acc[mr][mi] = (f32x4){0.f, 0.f, 0.f, 0.f};

  u32x4 ab4[4];   // A quad-buffer (issued 4 stages ahead; 1 load/thread/stage)
  s16x8 bb[2][8]; // B double-buffer (issued 2 stages ahead)
  const int a_elem = (m0 + rr) * 32 + seg * 8;       // + chunk*32768
  const int b_elem0 = (n0 + w * 32 + r) * 32 + q * 8;  // + mi*512 + chunk*65536

  auto issueA = [&](int s) {
    int c = s * 2 + ch_ld;
    const u16* base = A1h;
    if (TWOA && c >= 16) { base = A2h; c -= 16; }
    ab4[s & 3] = ld_sc1_x4(base + c * 32768 + a_elem);
  };
  auto issueB = [&](int s) {
    const int bi = s & 1;
#pragma unroll
    for (int i = 0; i < 8; ++i) {  // i = ch*4 + hl*2 + mi
      int ch = i >> 2, hl = (i >> 1) & 1, mi = i & 1;
      int c = s * 2 + ch;
      bb[bi][i] = ld_b16x8((hl ? WBl : WBh) + c * 65536 + b_elem0 + mi * 512);
    }
  };

  // prologue (in-order vmcnt accounting relies on this exact order)
  issueA(0); issueA(1); issueB(0); issueA(2); issueB(1); issueA(3);

#pragma unroll
  for (int s = 0; s < NST; ++s) {
    // retire A(s)+B(s); steady leaves A(s+2),B(s+1),A(s+3) = 10 in flight
    if (s + 3 < NST)      WAITVM(10);
    else if (s + 2 < NST) WAITVM(9);
    else if (s + 1 < NST) WAITVM(8);
    else                  WAITVM(0);
    pin(ab4[s & 3]);
#pragma unroll
    for (int i = 0; i < 8; ++i) pin(bb[s & 1][i]);
    u16* sAb = sA + (s & 1) * 2560;
    *(u32x4*)(sAb + (ch_ld * 32 + rr) * 40 + seg * 8) = ab4[s & 3];
    __syncthreads();  // single barrier/stage; parity-2 reuse distance is safe
#pragma unroll
    for (int ch = 0; ch < 2; ++ch)
#pragma unroll
      for (int mr = 0; mr < 2; ++mr) {
        const s16x8 ah = *(const s16x8*)(sAb + (ch * 32 + mr * 16 + r) * 40 + q * 8);
#pragma unroll
        for (int mi = 0; mi < 2; ++mi) {
          acc[mr][mi] = mfma_bf16(ah, bb[s & 1][ch * 4 + mi], acc[mr][mi]);
          acc[mr][mi] = mfma_bf16(ah, bb[s & 1][ch * 4 + 2 + mi], acc[mr][mi]);
        }
      }
    if (s + 2 < NST) issueB(s + 2);
    if (s + 4 < NST) issueA(s + 4);
  }

  if (HASX) {  // extra K=16 chunk from x_t (bf16-hi, padded to 32); weights chunk 16
#pragma unroll
    for (int mr = 0; mr < 2; ++mr) {
      s16x8 axh;
#pragma unroll
      for (int j = 0; j < 8; ++j) axh[j] = 0;
      if (q < 2) {
        const float* xp = P.x + (((long)(m0 + mr * 16 + r) * 336 + t) * 16 + q * 8);
        float4 v0 = *(const float4*)xp;
        float4 v1 = *(const float4*)(xp + 4);
        float vv[8] = {v0.x, v0.y, v0.z, v0.w, v1.x, v1.y, v1.z, v1.w};
#pragma unroll
        for (int j = 0; j < 8; ++j) axh[j] = (short)f2bf(vv[j]);
      }
#pragma unroll
      for (int mi = 0; mi < 2; ++mi) {
        long bo = ((long)16 * 2048 + n0 + w * 32 + mi * 16 + r) * 32 + q * 8;
        acc[mr][mi] = mfma_bf16(axh, *(const s16x8*)(WBh + bo), acc[mr][mi]);
        acc[mr][mi] = mfma_bf16(axh, *(const s16x8*)(WBl + bo), acc[mr][mi]);
      }
    }
  }

  // ---- epilogue: gates -> (c,h); cols gate-interleaved n'=h*4+g ----
  __syncthreads();
  float* gbuf = (float*)smem;  // [32][132] fp32 (132: float4-aligned, conflict-free)
#pragma unroll
  for (int mr = 0; mr < 2; ++mr)
#pragma unroll
    for (int mi = 0; mi < 2; ++mi)
#pragma unroll
      for (int reg = 0; reg < 4; ++reg)
        gbuf[(mr * 16 + q * 4 + reg) * 132 + (w * 32 + mi * 16 + r)] = acc[mr][mi][reg];
  __syncthreads();
  u16 hbv[4];
#pragma unroll
  for (int kk2 = 0; kk2 < 4; ++kk2) {
    int p = tid + kk2 * 256;
    int ml = p >> 5, hl2 = p & 31;
    f32x4 g4 = *(const f32x4*)(gbuf + ml * 132 + hl2 * 4);
    int nb = n0 + hl2 * 4;
    float g0 = g4[0] + bias_p[nb + 0];
    float g1 = g4[1] + bias_p[nb + 1];
    float g2 = g4[2] + bias_p[nb + 2];
    float g3 = g4[3] + bias_p[nb + 3];
    if (HASY) {
      float yv = yb[ml];
      g0 += yv * wyp[nb + 0];
      g1 += yv * wyp[nb + 1];
      g2 += yv * wyp[nb + 2];
      g3 += yv * wyp[nb + 3];
    }
    float ig = sigm(g0), fg = sigm(g1), gg = tanhf(g2), og = sigm(g3);
    float cn = fg * creg[kk2] + ig * gg;
    creg[kk2] = cn;
    hbv[kk2] = f2bf(og * tanhf(cn));
  }
  __syncthreads();
  u16* lh = (u16*)smem;  // [32][40]
#pragma unroll
  for (int kk2 = 0; kk2 < 4; ++kk2) {
    int p = tid + kk2 * 256;
    lh[(p >> 5) * 40 + (p & 31)] = hbv[kk2];
  }
  __syncthreads();
  if (tid < 128) {  // 32 rows x 4 segs x 16B = this block's h-hi slice (chunk n_tile)
    int rr2 = tid >> 2;
    st_sc1_x4(Hh + n_tile * 32768 + (m0 + rr2) * 32 + seg * 8,
              *(const u32x4*)(lh + rr2 * 40 + seg * 8));
  }
}

// ---------------- FC head (fused into dec0 phase): y = relu(relu(h1@W1^T+b1)@W2^T+b2)
// Each block computes FC for its own 32 rows (redundant across n_tiles; ~0.3us).
__device__ __forceinline__ void fc_inline(const KParams& P, int m_tile, int n_tile,
                                          const u16* Ah, int tOut, char* smem) {
  const int tid = threadIdx.x;
  const int w = tid >> 6, lane = tid & 63, r = lane & 15, q = lane >> 4;
  const int m0 = m_tile * 32;
  u16* sF = (u16*)smem;  // [16][32][40] u16 = 40960 B
  u32x4 vv[8];
#pragma unroll
  for (int j = 0; j < 8; ++j) {
    int idx = tid + j * 256;
    int c = idx >> 7, rw = (idx >> 2) & 31, sg = idx & 3;
    vv[j] = ld_sc1_x4(Ah + c * 32768 + (m0 + rw) * 32 + sg * 8);
  }
  wait_vm0();
#pragma unroll
  for (int j = 0; j < 8; ++j) pin(vv[j]);
#pragma unroll
  for (int j = 0; j < 8; ++j) {
    int idx = tid + j * 256;
    int c = idx >> 7, rw = (idx >> 2) & 31, sg = idx & 3;
    *(u32x4*)(sF + (c * 32 + rw) * 40 + sg * 8) = vv[j];
  }
  __syncthreads();
  f32x4 af[2][4];
#pragma unroll
  for (int mr = 0; mr < 2; ++mr)
#pragma unroll
    for (int mi = 0; mi < 4; ++mi) af[mr][mi] = (f32x4){0.f, 0.f, 0.f, 0.f};
  for (int c = 0; c < 16; ++c)
#pragma unroll
    for (int mr = 0; mr < 2; ++mr) {
      const s16x8 ah = *(const s16x8*)(sF + (c * 32 + mr * 16 + r) * 40 + q * 8);
#pragma unroll
      for (int mi = 0; mi < 4; ++mi) {
        int col = w * 64 + mi * 16 + r;
        af[mr][mi] = mfma_bf16(ah, *(const s16x8*)(P.wfh + (c * 256 + col) * 32 + q * 8),
                               af[mr][mi]);
      }
    }
  __syncthreads();
  float* hid = (float*)smem;  // [32][264]
#pragma unroll
  for (int mr = 0; mr < 2; ++mr)
#pragma unroll
    for (int mi = 0; mi < 4; ++mi)
#pragma unroll
      for (int reg = 0; reg < 4; ++reg) {
        int row = mr * 16 + q * 4 + reg, col = w * 64 + mi * 16 + r;
        hid[row * 264 + col] = fmaxf(af[mr][mi][reg] + P.fcb1[col], 0.f);
      }
  __syncthreads();
  float* part = (float*)(smem + 33792);  // [32][9]
  {
    int m = tid >> 3, sg = tid & 7;
    float s = 0.f;
#pragma unroll
    for (int j = 0; j < 32; ++j) s += hid[m * 264 + sg * 32 + j] * P.fcw2[sg * 32 + j];
    part[m * 9 + sg] = s;
  }
  __syncthreads();
  float* yb = (float*)(smem + 40960);  // [32], consumed by dec0 epilogue
  if (tid < 32) {
    float s = P.fcb2[0];
#pragma unroll
    for (int k = 0; k < 8; ++k) s += part[tid * 9 + k];
    float pred = fmaxf(s, 0.f);
    yb[tid] = pred;
    if (n_tile == 0) P.out[(long)(m0 + tid) * 168 + tOut] = pred;
  }
  __syncthreads();
}

// ---------------- persistent kernel ----------------
__global__ void __launch_bounds__(TPB, 2) lstm_seq(KParams P) {
  __shared__ __align__(16) char smem[41216];
  const int b = blockIdx.x;
  const int grp = b & 7;                   // barrier group / XCD hint
  const int idx = b >> 3;                  // 0..63
  const int n_tile = grp * 2 + (idx & 1);  // each group owns a 256-col slice (B L2-resident)
  const int m_tile = idx >> 1;             // 0..31
  const float* yb = (const float*)(smem + 40960);
  unsigned long long bi = 0;
  int p0 = 0, p1 = 0;  // h0[p0]/h1[p1] hold latest h
  float c0r[4], c1r[4];
#pragma unroll
  for (int i = 0; i < 4; ++i) { c0r[i] = 0.f; c1r[i] = 0.f; }

  // encoder, layer-pipelined: phase p computes enc0(t=p) and enc1(t=p-1)
  for (int p = 0; p <= 336; ++p) {
    if (p < 336)
      lstm_phase<16, false, true, false>(P, m_tile, n_tile, P.h0h[p0], nullptr,
                                         P.we0h, P.we0l, P.be0, nullptr, p, c0r,
                                         P.h0h[p0 ^ 1], smem, nullptr);
    if (p >= 1)
      lstm_phase<32, true, false, false>(P, m_tile, n_tile, P.h0h[p0], P.h1h[p1],
                                         P.we1h, P.we1l, P.be1, nullptr, 0, c1r,
                                         P.h1h[p1 ^ 1], smem, nullptr);
    if (p < 336) p0 ^= 1;
    if (p >= 1) p1 ^= 1;
    ++bi; gbar(P, grp, bi);
  }
  // decoder: per t, phase A = [fc(t-1) + dec0(t)], phase B = dec1(t); 2 barriers/t
  for (int t = 0; t < 168; ++t) {
    if (t > 0) {
      fc_inline(P, m_tile, n_tile, P.h1h[p1], t - 1, smem);
    } else {
      if (threadIdx.x < 32) ((float*)(smem + 40960))[threadIdx.x] = 0.f;
      __syncthreads();
    }
    lstm_phase<16, false, false, true>(P, m_tile, n_tile, P.h0h[p0], nullptr,
                                       P.wd0h, P.wd0l, P.bd0, P.wyp, 0, c0r,
                                       P.h0h[p0 ^ 1], smem, yb);
    p0 ^= 1; ++bi; gbar(P, grp, bi);
    lstm_phase<32, true, false, false>(P, m_tile, n_tile, P.h0h[p0], P.h1h[p1],
                                       P.wd1h, P.wd1l, P.bd1, nullptr, 0, c1r,
                                       P.h1h[p1 ^ 1], smem, nullptr);
    p1 ^= 1; ++bi; gbar(P, grp, bi);
  }
  fc_inline(P, m_tile, n_tile, P.h1h[p1], 167, smem);  // trailing fc for last step
}

// ---------------- host ----------------
extern "C" void kernel_launch(void* const* d_in, const int* in_sizes, int n_in,
                              void* d_out, int out_size, void* d_ws, size_t ws_size,
                              hipStream_t stream) {
  const float* x     = (const float*)d_in[0];
  const float* eWih0 = (const float*)d_in[1];
  const float* eWhh0 = (const float*)d_in[2];
  const float* eb0   = (const float*)d_in[3];
  const float* eWih1 = (const float*)d_in[4];
  const float* eWhh1 = (const float*)d_in[5];
  const float* eb1   = (const float*)d_in[6];
  const float* dWih0 = (const float*)d_in[7];
  const float* dWhh0 = (const float*)d_in[8];
  const float* db0   = (const float*)d_in[9];
  const float* dWih1 = (const float*)d_in[10];
  const float* dWhh1 = (const float*)d_in[11];
  const float* db1   = (const float*)d_in[12];
  const float* fcW1  = (const float*)d_in[13];
  const float* fcb1  = (const float*)d_in[14];
  const float* fcW2  = (const float*)d_in[15];
  const float* fcb2  = (const float*)d_in[16];

  char* ws = (char*)d_ws;
  unsigned long long* cx = (unsigned long long*)(ws + 0);     // 8 counters, 256B apart
  unsigned long long* cg = (unsigned long long*)(ws + 2048);
  char* hb = ws + 8192;
  u16* h0h0 = (u16*)(hb + 0L * 1048576);
  u16* h0h1 = (u16*)(hb + 1L * 1048576);
  u16* h1h0 = (u16*)(hb + 2L * 1048576);
  u16* h1h1 = (u16*)(hb + 3L * 1048576);
  char* wb = hb + 4L * 1048576;
  u16* we0h = (u16*)wb; wb += 2228224L;
  u16* we0l = (u16*)wb; wb += 2228224L;
  u16* we1h = (u16*)wb; wb += 4194304L;
  u16* we1l = (u16*)wb; wb += 4194304L;
  u16* wd0h = (u16*)wb; wb += 2097152L;
  u16* wd0l = (u16*)wb; wb += 2097152L;
  u16* wd1h = (u16*)wb; wb += 4194304L;
  u16* wd1l = (u16*)wb; wb += 4194304L;
  u16* wfh  = (u16*)wb; wb += 262144L;
  float* be0 = (float*)wb; wb += 8192L;
  float* be1 = (float*)wb; wb += 8192L;
  float* bd0 = (float*)wb; wb += 8192L;
  float* bd1 = (float*)wb; wb += 8192L;
  float* wyp = (float*)wb; wb += 8192L;

  long zbytes = 8192L + 4L * 1048576L;  // barrier counters + h-hi ping-pong buffers
  zero_ws<<<1024, 256, 0, stream>>>((uint4*)ws, zbytes / 16);
  prep_w<<<2048, 256, 0, stream>>>(eWih0, eWhh0, eb0, we0h, we0l, be0, nullptr, 0, 17);
  prep_w<<<2048, 256, 0, stream>>>(eWih1, eWhh1, eb1, we1h, we1l, be1, nullptr, 1, 32);
  prep_w<<<2048, 256, 0, stream>>>(dWih0, dWhh0, db0, wd0h, wd0l, bd0, wyp, 2, 16);
  prep_w<<<2048, 256, 0, stream>>>(dWih1, dWhh1, db1, wd1h, wd1l, bd1, nullptr, 1, 32);
  prep_fc<<<512, 256, 0, stream>>>(fcW1, wfh);

  KParams P;
  P.x = x; P.out = (float*)d_out; P.cx = cx; P.cg = cg;
  P.h0h[0] = h0h0; P.h0h[1] = h0h1;
  P.h1h[0] = h1h0; P.h1h[1] = h1h1;
  P.we0h = we0h; P.we0l = we0l; P.we1h = we1h; P.we1l = we1l;
  P.wd0h = wd0h; P.wd0l = wd0l; P.wd1h = wd1h; P.wd1l = wd1l;
  P.wfh = wfh;
  P.be0 = be0; P.be1 = be1; P.bd0 = bd0; P.bd1 = bd1; P.wyp = wyp;
  P.fcb1 = fcb1; P.fcw2 = fcW2; P.fcb2 = fcb2;

  lstm_seq<<<NBLK, TPB, 0, stream>>>(P);
}

// Round 6
// 26323.904 us; speedup vs baseline: 1.6533x; 1.6533x over previous
//
#include <hip/hip_runtime.h>
#include <math.h>

#define TPB 256
#define NBLK 256

typedef unsigned short u16;
typedef float f32x4 __attribute__((ext_vector_type(4)));
typedef short s16x8 __attribute__((ext_vector_type(8)));
typedef unsigned int u32x4 __attribute__((ext_vector_type(4)));

// ---------------- helpers ----------------
__device__ __forceinline__ u16 f2bf(float f) {
  unsigned u = __float_as_uint(f);
  unsigned r = (u + 0x7FFFu + ((u >> 16) & 1u)) >> 16;   // RNE
  return (u16)r;
}
__device__ __forceinline__ float bf2f(u16 b) { return __uint_as_float(((unsigned)b) << 16); }
__device__ __forceinline__ float sigm(float x) { return 1.f / (1.f + expf(-x)); }

__device__ __forceinline__ f32x4 mfma_bf16(s16x8 a, s16x8 b, f32x4 c) {
  return __builtin_amdgcn_mfma_f32_16x16x32_bf16(a, b, c, 0, 0, 0);
}

// ---- asm memory ops. sc1 = device scope (meet at LLC); plain = cached (L1/L2).
// All K-loop VMEM is asm so manual vmcnt accounting is exact.
__device__ __forceinline__ u32x4 ld_sc1_x4(const void* p) {
  u32x4 d;
  asm volatile("global_load_dwordx4 %0, %1, off sc1"
               : "=v"(d) : "v"((unsigned long long)p) : "memory");
  return d;
}
__device__ __forceinline__ s16x8 ld_b16x8(const void* p) {  // cached (weights)
  s16x8 d;
  asm volatile("global_load_dwordx4 %0, %1, off"
               : "=v"(d) : "v"((unsigned long long)p) : "memory");
  return d;
}
__device__ __forceinline__ void st_sc1_x4(void* p, u32x4 v) {
  asm volatile("global_store_dwordx4 %0, %1, off sc1"
               :: "v"((unsigned long long)p), "v"(v) : "memory");
}
__device__ __forceinline__ void wait_vm0() { asm volatile("s_waitcnt vmcnt(0)" ::: "memory"); }
#define WAITVM(n) asm volatile("s_waitcnt vmcnt(" #n ")" ::: "memory")
__device__ __forceinline__ void pin(u32x4& v) { asm volatile("" : "+v"(v)); }
__device__ __forceinline__ void pin(s16x8& v) { asm volatile("" : "+v"(v)); }

// ---------------- params ----------------
struct KParams {
  const float* x;          // [1024][336][16]
  float* out;              // [1024][168]
  unsigned long long* cx;  // per-group barrier counters (stride 32 ULL = 256B)
  unsigned long long* cg;  // global barrier counter
  u16* h0h[2]; u16* h1h[2];  // h frag-layout [16][1024][32] bf16 HI only, ping-pong (sc1)
  const u16 *we0h, *we0l;    // [17][2048][32] (chunk 16 = x weights)
  const u16 *we1h, *we1l;    // [32][2048][32]
  const u16 *wd0h, *wd0l;    // [16][2048][32]
  const u16 *wd1h, *wd1l;    // [32][2048][32]
  const u16 *wfh;            // [16][256][32] (hi only)
  const float *be0, *be1, *bd0, *bd1, *wyp;  // permuted biases [2048], dec0 y-column [2048]
  const float *fcb1, *fcw2, *fcb2;           // raw fp32 from inputs
};

// ---------------- init kernels ----------------
__global__ void zero_ws(uint4* p, long n) {
  uint4 z = {0u, 0u, 0u, 0u};
  for (long i = (long)blockIdx.x * blockDim.x + threadIdx.x; i < n; i += (long)gridDim.x * blockDim.x)
    p[i] = z;
}

// Build fragment-major, gate-interleaved, hi/lo-split weights.
// dst[c][n'][kk], n' = h*4+g  (orig row n = g*512+h), k = c*32+kk.
__global__ void prep_w(const float* __restrict__ Wih, const float* __restrict__ Whh,
                       const float* __restrict__ bias,
                       u16* __restrict__ dhi, u16* __restrict__ dlo,
                       float* __restrict__ bias_p, float* __restrict__ wy_p,
                       int mode, int nchunks) {
  long total = (long)nchunks * 2048 * 32;
  for (long i = (long)blockIdx.x * blockDim.x + threadIdx.x; i < total; i += (long)gridDim.x * blockDim.x) {
    int kk = (int)(i & 31);
    long r1 = i >> 5;
    int n = (int)(r1 & 2047);
    int c = (int)(r1 >> 11);
    int h = n >> 2, g = n & 3;
    int no = g * 512 + h;
    float wv;
    if (mode == 0)      wv = (c < 16) ? Whh[no * 512 + c * 32 + kk] : (kk < 16 ? Wih[no * 16 + kk] : 0.f);
    else if (mode == 1) wv = (c < 16) ? Wih[no * 512 + c * 32 + kk] : Whh[no * 512 + (c - 16) * 32 + kk];
    else                wv = Whh[no * 512 + c * 32 + kk];
    u16 hb = f2bf(wv);
    dhi[i] = hb;
    dlo[i] = f2bf(wv - bf2f(hb));
    if (i < 2048) {
      int nn = (int)i, hh = nn >> 2, gg = nn & 3, noo = gg * 512 + hh;
      bias_p[nn] = bias[noo];
      if (mode == 2) wy_p[nn] = Wih[noo];  // dec_Wih0 is [2048][1]
    }
  }
}

__global__ void prep_fc(const float* __restrict__ W1, u16* __restrict__ dhi) {
  int total = 16 * 256 * 32;
  for (int i = blockIdx.x * blockDim.x + threadIdx.x; i < total; i += gridDim.x * blockDim.x) {
    int kk = i & 31, n = (i >> 5) & 255, c = i >> 13;
    dhi[i] = f2bf(W1[n * 512 + c * 32 + kk]);
  }
}

// ---------------- fence-free grid barrier: one arrival per block ----------------
__device__ __forceinline__ void gbar(const KParams& P, int grp, unsigned long long bi) {
  wait_vm0();       // this wave's sc1 stores are at the LLC
  __syncthreads();  // all 4 waves drained
  if (threadIdx.x == 0) {
    unsigned long long old =
        __hip_atomic_fetch_add(&P.cx[grp * 32], 1ULL, __ATOMIC_RELAXED, __HIP_MEMORY_SCOPE_AGENT);
    if (old == bi * 32ULL - 1ULL)
      __hip_atomic_fetch_add(P.cg, 1ULL, __ATOMIC_RELAXED, __HIP_MEMORY_SCOPE_AGENT);
    unsigned long long t0 = __builtin_amdgcn_s_memrealtime();
    while (__hip_atomic_load(P.cg, __ATOMIC_RELAXED, __HIP_MEMORY_SCOPE_AGENT) < bi * 8ULL) {
      __builtin_amdgcn_s_sleep(2);
      if (__builtin_amdgcn_s_memrealtime() - t0 > 300000000ULL) {  // ~3 s
        P.out[0] = 1e9f;  // sentinel: barrier timeout
        break;
      }
    }
  }
  __syncthreads();
}

// ---------------- fused gates GEMM + LSTM cell ----------------
// 64m x 128n tile (256 blocks = 16 m x 16 n, 1/CU). A = activations bf16 HI only
// (sc1 from LLC) staged via double-buffered LDS, issued SIX stages ahead; B =
// weights bf16 hi+lo from L2, issued two ahead. Exact FIFO vmcnt: steady 18.
template <int NCT, bool TWOA, bool HASX, bool HASY>
__device__ __forceinline__ void lstm_phase(
    const KParams& P, int m_tile, int n_tile,
    const u16* A1h, const u16* A2h,
    const u16* WBh, const u16* WBl,
    const float* __restrict__ bias_p, const float* __restrict__ wyp, int t,
    float (&creg)[8], u16* Hh, char* smem, const float* yb) {
  constexpr int NST = NCT / 2;
  const int tid = threadIdx.x;
  const int w = tid >> 6, lane = tid & 63, r = lane & 15, q = lane >> 4;
  const int m0 = m_tile * 64, n0 = n_tile * 128;
  u16* sA = (u16*)smem;  // 2 bufs x [2ch][64r][40] u16 = 20480 B
  const int rr = (tid >> 2) & 63, seg = tid & 3;

  f32x4 acc[4][2];
#pragma unroll
  for (int mr = 0; mr < 4; ++mr)
#pragma unroll
    for (int mi = 0; mi < 2; ++mi) acc[mr][mi] = (f32x4){0.f, 0.f, 0.f, 0.f};

  u32x4 ab[12];    // A 6-stage lookahead x 2 chunks
  s16x8 bb[2][8];  // B 2-stage lookahead
  const int a_elem = (m0 + rr) * 32 + seg * 8;        // + chunk*32768
  const int b_elem = (n0 + w * 32 + r) * 32 + q * 8;  // + mi*512 + chunk*65536

  auto issueA = [&](int s) {
#pragma unroll
    for (int ch = 0; ch < 2; ++ch) {
      int c = s * 2 + ch;
      const u16* base = A1h;
      if (TWOA && c >= 16) { base = A2h; c -= 16; }
      ab[(s % 6) * 2 + ch] = ld_sc1_x4(base + c * 32768 + a_elem);
    }
  };
  auto issueB = [&](int s) {
#pragma unroll
    for (int i = 0; i < 8; ++i) {  // i = ch*4 + hl*2 + mi
      int ch = i >> 2, hl = (i >> 1) & 1, mi = i & 1;
      int c = s * 2 + ch;
      bb[s & 1][i] = ld_b16x8((hl ? WBl : WBh) + c * 65536 + b_elem + mi * 512);
    }
  };

  // prologue; FIFO order matters: A0 B0 A1 B1 A2 A3 A4 A5  (NST >= 6 always)
  issueA(0); issueB(0); issueA(1); issueB(1);
  issueA(2); issueA(3); issueA(4); issueA(5);

#pragma unroll
  for (int s = 0; s < NST; ++s) {
    const int rem = NST - 1 - s;
    // retire A(s)+B(s); leave 2*min(5,rem) A-loads + 8*min(1,rem) B-loads
    if (rem >= 5)      WAITVM(18);
    else if (rem == 4) WAITVM(16);
    else if (rem == 3) WAITVM(14);
    else if (rem == 2) WAITVM(12);
    else if (rem == 1) WAITVM(10);
    else               WAITVM(0);
    pin(ab[(s % 6) * 2 + 0]); pin(ab[(s % 6) * 2 + 1]);
#pragma unroll
    for (int i = 0; i < 8; ++i) pin(bb[s & 1][i]);
    u16* sAb = sA + (s & 1) * 5120;
    *(u32x4*)(sAb + (0 * 64 + rr) * 40 + seg * 8) = ab[(s % 6) * 2 + 0];
    *(u32x4*)(sAb + (1 * 64 + rr) * 40 + seg * 8) = ab[(s % 6) * 2 + 1];
    __syncthreads();  // one barrier/stage; double buffer covers the rest
#pragma unroll
    for (int ch = 0; ch < 2; ++ch)
#pragma unroll
      for (int mr = 0; mr < 4; ++mr) {
        const s16x8 ah = *(const s16x8*)(sAb + (ch * 64 + mr * 16 + r) * 40 + q * 8);
#pragma unroll
        for (int mi = 0; mi < 2; ++mi) {
          acc[mr][mi] = mfma_bf16(ah, bb[s & 1][ch * 4 + mi], acc[mr][mi]);       // B hi
          acc[mr][mi] = mfma_bf16(ah, bb[s & 1][ch * 4 + 2 + mi], acc[mr][mi]);   // B lo
        }
      }
    if (s + 2 < NST) issueB(s + 2);
    if (s + 6 < NST) issueA(s + 6);
  }

  if (HASX) {  // extra K=16 chunk from x_t (bf16-hi, padded to 32); weights chunk 16
#pragma unroll
    for (int mr = 0; mr < 4; ++mr) {
      s16x8 axh;
#pragma unroll
      for (int j = 0; j < 8; ++j) axh[j] = 0;
      if (q < 2) {
        const float* xp = P.x + (((long)(m0 + mr * 16 + r) * 336 + t) * 16 + q * 8);
        float4 v0 = *(const float4*)xp;
        float4 v1 = *(const float4*)(xp + 4);
        float vv[8] = {v0.x, v0.y, v0.z, v0.w, v1.x, v1.y, v1.z, v1.w};
#pragma unroll
        for (int j = 0; j < 8; ++j) axh[j] = (short)f2bf(vv[j]);
      }
#pragma unroll
      for (int mi = 0; mi < 2; ++mi) {
        long bo = ((long)16 * 2048 + n0 + w * 32 + mi * 16 + r) * 32 + q * 8;
        acc[mr][mi] = mfma_bf16(axh, *(const s16x8*)(WBh + bo), acc[mr][mi]);
        acc[mr][mi] = mfma_bf16(axh, *(const s16x8*)(WBl + bo), acc[mr][mi]);
      }
    }
  }

  // ---- epilogue: gates -> (c,h); cols gate-interleaved n'=h*4+g ----
  __syncthreads();
  float* gbuf = (float*)smem;  // [64][132] fp32, float4-aligned conflict-free
#pragma unroll
  for (int mr = 0; mr < 4; ++mr)
#pragma unroll
    for (int mi = 0; mi < 2; ++mi)
#pragma unroll
      for (int reg = 0; reg < 4; ++reg)
        gbuf[(mr * 16 + q * 4 + reg) * 132 + (w * 32 + mi * 16 + r)] = acc[mr][mi][reg];
  __syncthreads();
  u16 hbv[8];
#pragma unroll
  for (int kk2 = 0; kk2 < 8; ++kk2) {
    int p = tid + kk2 * 256;
    int ml = p >> 5, hl2 = p & 31;
    f32x4 g4 = *(const f32x4*)(gbuf + ml * 132 + hl2 * 4);
    int nb = n0 + hl2 * 4;
    float g0 = g4[0] + bias_p[nb + 0];
    float g1 = g4[1] + bias_p[nb + 1];
    float g2 = g4[2] + bias_p[nb + 2];
    float g3 = g4[3] + bias_p[nb + 3];
    if (HASY) {
      float yv = yb[ml];
      g0 += yv * wyp[nb + 0];
      g1 += yv * wyp[nb + 1];
      g2 += yv * wyp[nb + 2];
      g3 += yv * wyp[nb + 3];
    }
    float ig = sigm(g0), fg = sigm(g1), gg = tanhf(g2), og = sigm(g3);
    float cn = fg * creg[kk2] + ig * gg;
    creg[kk2] = cn;
    hbv[kk2] = f2bf(og * tanhf(cn));
  }
  __syncthreads();
  u16* lh = (u16*)smem;  // [64][40]
#pragma unroll
  for (int kk2 = 0; kk2 < 8; ++kk2) {
    int p = tid + kk2 * 256;
    lh[(p >> 5) * 40 + (p & 31)] = hbv[kk2];
  }
  __syncthreads();
  st_sc1_x4(Hh + (n_tile * 1024 + m0 + rr) * 32 + seg * 8,
            *(const u32x4*)(lh + rr * 40 + seg * 8));
}

// ---------------- FC head (fused into dec0 phase, own 64 rows, all blocks) ----
// y = relu(relu(h1@W1^T+b1)@W2^T+b2). Two K=256 passes through 40 KB LDS.
__device__ __forceinline__ void fc_inline(const KParams& P, int m_tile, int n_tile,
                                          const u16* Ah, int tOut, char* smem) {
  const int tid = threadIdx.x;
  const int w = tid >> 6, lane = tid & 63, r = lane & 15, q = lane >> 4;
  const int m0 = m_tile * 64;
  u16* sF = (u16*)smem;  // [8ch][64r][40]
  f32x4 af[4][4];
#pragma unroll
  for (int mr = 0; mr < 4; ++mr)
#pragma unroll
    for (int mi = 0; mi < 4; ++mi) af[mr][mi] = (f32x4){0.f, 0.f, 0.f, 0.f};

  const int ch_l = tid >> 8;  // unused placeholder
  (void)ch_l;
  u32x4 v1[8], v2[8];
#pragma unroll
  for (int j = 0; j < 8; ++j) {
    int idx = tid + j * 256;
    int c = idx >> 8, rw = (idx >> 2) & 63, sg = idx & 3;
    v1[j] = ld_sc1_x4(Ah + c * 32768 + (m0 + rw) * 32 + sg * 8);
  }
#pragma unroll
  for (int j = 0; j < 8; ++j) {
    int idx = tid + j * 256;
    int c = (idx >> 8) + 8, rw = (idx >> 2) & 63, sg = idx & 3;
    v2[j] = ld_sc1_x4(Ah + c * 32768 + (m0 + rw) * 32 + sg * 8);
  }
  WAITVM(8);
#pragma unroll
  for (int j = 0; j < 8; ++j) pin(v1[j]);
#pragma unroll
  for (int j = 0; j < 8; ++j) {
    int idx = tid + j * 256;
    int c = idx >> 8, rw = (idx >> 2) & 63, sg = idx & 3;
    *(u32x4*)(sF + (c * 64 + rw) * 40 + sg * 8) = v1[j];
  }
  __syncthreads();
#pragma unroll
  for (int pass = 0; pass < 2; ++pass) {
    for (int c = 0; c < 8; ++c)
#pragma unroll
      for (int mr = 0; mr < 4; ++mr) {
        const s16x8 ah = *(const s16x8*)(sF + (c * 64 + mr * 16 + r) * 40 + q * 8);
#pragma unroll
        for (int mi = 0; mi < 4; ++mi) {
          int col = w * 64 + mi * 16 + r;
          af[mr][mi] = mfma_bf16(
              ah, *(const s16x8*)(P.wfh + ((pass * 8 + c) * 256 + col) * 32 + q * 8),
              af[mr][mi]);
        }
      }
    if (pass == 0) {
      wait_vm0();
#pragma unroll
      for (int j = 0; j < 8; ++j) pin(v2[j]);
      __syncthreads();
#pragma unroll
      for (int j = 0; j < 8; ++j) {
        int idx = tid + j * 256;
        int c = idx >> 8, rw = (idx >> 2) & 63, sg = idx & 3;
        *(u32x4*)(sF + (c * 64 + rw) * 40 + sg * 8) = v2[j];
      }
      __syncthreads();
    }
  }
  __syncthreads();
  u16* hidb = (u16*)smem;  // [64][264] bf16
#pragma unroll
  for (int mr = 0; mr < 4; ++mr)
#pragma unroll
    for (int mi = 0; mi < 4; ++mi)
#pragma unroll
      for (int reg = 0; reg < 4; ++reg) {
        int row = mr * 16 + q * 4 + reg, col = w * 64 + mi * 16 + r;
        hidb[row * 264 + col] = f2bf(fmaxf(af[mr][mi][reg] + P.fcb1[col], 0.f));
      }
  __syncthreads();
  float* part = (float*)(smem + 33792);  // [64][5]
  {
    int m = tid >> 2, sg = tid & 3;
    float s = 0.f;
#pragma unroll
    for (int j = 0; j < 64; ++j)
      s += bf2f(hidb[m * 264 + sg * 64 + j]) * P.fcw2[sg * 64 + j];
    part[m * 5 + sg] = s;
  }
  __syncthreads();
  float* yb = (float*)(smem + 40960);  // [64], consumed by dec0 epilogue
  if (tid < 64) {
    float s = P.fcb2[0] + part[tid * 5 + 0] + part[tid * 5 + 1] +
              part[tid * 5 + 2] + part[tid * 5 + 3];
    float pred = fmaxf(s, 0.f);
    yb[tid] = pred;
    if (n_tile == 0) P.out[(long)(m0 + tid) * 168 + tOut] = pred;
  }
  __syncthreads();
}

// ---------------- persistent kernel ----------------
__global__ void __launch_bounds__(TPB, 1) lstm_seq(KParams P) {
  __shared__ __align__(16) char smem[41216];
  const int b = blockIdx.x;
  const int grp = b & 7;                   // barrier group / XCD (round-robin dispatch)
  const int idx = b >> 3;                  // 0..31
  const int n_tile = grp * 2 + (idx & 1);  // 2 slabs/XCD -> ~3.1 MB L2-resident weights
  const int m_tile = idx >> 1;             // 0..15
  const float* yb = (const float*)(smem + 40960);
  unsigned long long bi = 0;
  int p0 = 0, p1 = 0;
  float c0r[8], c1r[8];
#pragma unroll
  for (int i = 0; i < 8; ++i) { c0r[i] = 0.f; c1r[i] = 0.f; }

  // encoder, layer-pipelined: phase p computes enc0(t=p) and enc1(t=p-1)
  for (int p = 0; p <= 336; ++p) {
    if (p < 336)
      lstm_phase<16, false, true, false>(P, m_tile, n_tile, P.h0h[p0], nullptr,
                                         P.we0h, P.we0l, P.be0, nullptr, p, c0r,
                                         P.h0h[p0 ^ 1], smem, nullptr);
    if (p >= 1)
      lstm_phase<32, true, false, false>(P, m_tile, n_tile, P.h0h[p0], P.h1h[p1],
                                         P.we1h, P.we1l, P.be1, nullptr, 0, c1r,
                                         P.h1h[p1 ^ 1], smem, nullptr);
    if (p < 336) p0 ^= 1;
    if (p >= 1) p1 ^= 1;
    ++bi; gbar(P, grp, bi);
  }
  // decoder: phase A = [fc(t-1) + dec0(t)], phase B = dec1(t); 2 barriers/step
  for (int t = 0; t < 168; ++t) {
    if (t > 0) {
      fc_inline(P, m_tile, n_tile, P.h1h[p1], t - 1, smem);
    } else {
      if (threadIdx.x < 64) ((float*)(smem + 40960))[threadIdx.x] = 0.f;
      __syncthreads();
    }
    lstm_phase<16, false, false, true>(P, m_tile, n_tile, P.h0h[p0], nullptr,
                                       P.wd0h, P.wd0l, P.bd0, P.wyp, 0, c0r,
                                       P.h0h[p0 ^ 1], smem, yb);
    p0 ^= 1; ++bi; gbar(P, grp, bi);
    lstm_phase<32, true, false, false>(P, m_tile, n_tile, P.h0h[p0], P.h1h[p1],
                                       P.wd1h, P.wd1l, P.bd1, nullptr, 0, c1r,
                                       P.h1h[p1 ^ 1], smem, nullptr);
    p1 ^= 1; ++bi; gbar(P, grp, bi);
  }
  fc_inline(P, m_tile, n_tile, P.h1h[p1], 167, smem);  // trailing fc
}

// ---------------- host ----------------
extern "C" void kernel_launch(void* const* d_in, const int* in_sizes, int n_in,
                              void* d_out, int out_size, void* d_ws, size_t ws_size,
                              hipStream_t stream) {
  const float* x     = (const float*)d_in[0];
  const float* eWih0 = (const float*)d_in[1];
  const float* eWhh0 = (const float*)d_in[2];
  const float* eb0   = (const float*)d_in[3];
  const float* eWih1 = (const float*)d_in[4];
  const float* eWhh1 = (const float*)d_in[5];
  const float* eb1   = (const float*)d_in[6];
  const float* dWih0 = (const float*)d_in[7];
  const float* dWhh0 = (const float*)d_in[8];
  const float* db0   = (const float*)d_in[9];
  const float* dWih1 = (const float*)d_in[10];
  const float* dWhh1 = (const float*)d_in[11];
  const float* db1   = (const float*)d_in[12];
  const float* fcW1  = (const float*)d_in[13];
  const float* fcb1  = (const float*)d_in[14];
  const float* fcW2  = (const float*)d_in[15];
  const float* fcb2  = (const float*)d_in[16];

  char* ws = (char*)d_ws;
  unsigned long long* cx = (unsigned long long*)(ws + 0);
  unsigned long long* cg = (unsigned long long*)(ws + 2048);
  char* hb = ws + 8192;
  u16* h0h0 = (u16*)(hb + 0L * 1048576);
  u16* h0h1 = (u16*)(hb + 1L * 1048576);
  u16* h1h0 = (u16*)(hb + 2L * 1048576);
  u16* h1h1 = (u16*)(hb + 3L * 1048576);
  char* wb = hb + 4L * 1048576;
  u16* we0h = (u16*)wb; wb += 2228224L;
  u16* we0l = (u16*)wb; wb += 2228224L;
  u16* we1h = (u16*)wb; wb += 4194304L;
  u16* we1l = (u16*)wb; wb += 4194304L;
  u16* wd0h = (u16*)wb; wb += 2097152L;
  u16* wd0l = (u16*)wb; wb += 2097152L;
  u16* wd1h = (u16*)wb; wb += 4194304L;
  u16* wd1l = (u16*)wb; wb += 4194304L;
  u16* wfh  = (u16*)wb; wb += 262144L;
  float* be0 = (float*)wb; wb += 8192L;
  float* be1 = (float*)wb; wb += 8192L;
  float* bd0 = (float*)wb; wb += 8192L;
  float* bd1 = (float*)wb; wb += 8192L;
  float* wyp = (float*)wb; wb += 8192L;

  long zbytes = 8192L + 4L * 1048576L;  // barrier counters + h-hi ping-pong buffers
  zero_ws<<<1024, 256, 0, stream>>>((uint4*)ws, zbytes / 16);
  prep_w<<<2048, 256, 0, stream>>>(eWih0, eWhh0, eb0, we0h, we0l, be0, nullptr, 0, 17);
  prep_w<<<2048, 256, 0, stream>>>(eWih1, eWhh1, eb1, we1h, we1l, be1, nullptr, 1, 32);
  prep_w<<<2048, 256, 0, stream>>>(dWih0, dWhh0, db0, wd0h, wd0l, bd0, wyp, 2, 16);
  prep_w<<<2048, 256, 0, stream>>>(dWih1, dWhh1, db1, wd1h, wd1l, bd1, nullptr, 1, 32);
  prep_fc<<<512, 256, 0, stream>>>(fcW1, wfh);

  KParams P;
  P.x = x; P.out = (float*)d_out; P.cx = cx; P.cg = cg;
  P.h0h[0] = h0h0; P.h0h[1] = h0h1;
  P.h1h[0] = h1h0; P.h1h[1] = h1h1;
  P.we0h = we0h; P.we0l = we0l; P.we1h = we1h; P.we1l = we1l;
  P.wd0h = wd0h; P.wd0l = wd0l; P.wd1h = wd1h; P.wd1l = wd1l;
  P.wfh = wfh;
  P.be0 = be0; P.be1 = be1; P.bd0 = bd0; P.bd1 = bd1; P.wyp = wyp;
  P.fcb1 = fcb1; P.fcw2 = fcW2; P.fcb2 = fcb2;

  lstm_seq<<<NBLK, TPB, 0, stream>>>(P);
}